// Round 14
// baseline (70.620 us; speedup 1.0000x reference)
//
#include <hip/hip_runtime.h>
#include <hip/hip_bf16.h>

#define NROWS 8192
#define DIM 256
#define NSPLIT 16
#define JSPAN (NROWS / NSPLIT)   /* 512 cols per block */
#define NGRP (JSPAN / 16)        /* 32 16-col groups per wave */
#define RPW 64                   /* rows per wave (A stationary) */
#define RPB 256                  /* rows per block (4 waves) */
#define GRP_BYTES 8192           /* 16 cols x 512 B, K-major-grouped */

typedef __bf16 bf16x8 __attribute__((ext_vector_type(8)));
typedef float f32x4 __attribute__((ext_vector_type(4)));

#define NEG_LOG2E -1.4426950408889634f
#define NEG_LN2   -0.6931471805599453f

// ---- Kernel 1: L2-normalize rows, fp32 -> bf16; zero accums ----
// En: row-major, scaled by -log2(e) (GEMM acc = -log2e*sim; exp(-sim)=exp2(acc)).
// Qn: K-MAJOR-GROUPED. Group g = cols [16g,16g+16); chunk kk (1 KB) = the 16
// cols' 64B K-slice kk, col-interleaved at 64B:
//   byte(col=16g+c, kbyte=kk*64+b) -> Qn + g*8192 + kk*1024 + c*64 + b.
// A wave's B-fragment load for (group g, kk) covers the contiguous 1KB chunk
// (lane reads 16B at (lane&15)*64 + (lane>>4)*16): 8 full 128B lines/instr.
__global__ __launch_bounds__(256) void k_normalize_all(const float* __restrict__ emb,
                                                       const float* __restrict__ qry,
                                                       __hip_bfloat16* __restrict__ En,
                                                       __hip_bfloat16* __restrict__ Qn,
                                                       float* __restrict__ rowsum,
                                                       float* __restrict__ out) {
    if (blockIdx.x < 8)
        reinterpret_cast<float4*>(rowsum)[blockIdx.x * 256 + threadIdx.x] =
            float4{0.f, 0.f, 0.f, 0.f};
    if (blockIdx.x == 8 && threadIdx.x == 0) out[0] = 0.f;

    const int gr   = blockIdx.x * 4 + (threadIdx.x >> 6);
    const int lane = threadIdx.x & 63;
    const bool isE = (gr < NROWS);
    const float* in = isE ? emb : qry;
    const int row   = isE ? gr : gr - NROWS;
    const float scale = isE ? NEG_LOG2E : 1.0f;

    const float4 v = reinterpret_cast<const float4*>(in + (size_t)row * DIM)[lane];
    float ss = v.x * v.x + v.y * v.y + v.z * v.z + v.w * v.w;
#pragma unroll
    for (int m = 32; m >= 1; m >>= 1) ss += __shfl_xor(ss, m, 64);
    const float inv = scale / fmaxf(sqrtf(ss), 1e-8f);
    __hip_bfloat16 o[4];
    o[0] = __float2bfloat16(v.x * inv);
    o[1] = __float2bfloat16(v.y * inv);
    o[2] = __float2bfloat16(v.z * inv);
    o[3] = __float2bfloat16(v.w * inv);
    const ushort4 o8 = *reinterpret_cast<const ushort4*>(o);

    if (isE) {
        reinterpret_cast<ushort4*>(En + (size_t)row * DIM)[lane] = o8;
    } else {
        // Lane's 8B = K-bytes [lane*8, lane*8+8) of this col's 512B row.
        const int g = row >> 4, c = row & 15;
        char* dst = (char*)Qn + (size_t)g * GRP_BYTES
                    + (size_t)(lane >> 3) * 1024 + c * 64 + (lane & 7) * 8;
        *reinterpret_cast<ushort4*>(dst) = o8;
    }
}

// ---- Kernel 2: fused sim-GEMM + row sum of exp(-s) ----
// NO LDS, NO barriers, NO DMA engine: each wave streams its B groups straight
// from global (L2-resident; 8 full 128B lines per load instruction thanks to
// the K-major-grouped layout - fixing round 8's half-line scatter) into a
// depth-2 register pipeline (named bA/bB, rule #20). Counted vmcnt(8) per
// step; the serial chain is just load->MFMA. A stationary: a[4][8], 128 VGPR.
__global__ __launch_bounds__(256, 2) void k_simlse(const __hip_bfloat16* __restrict__ En,
                                                   const __hip_bfloat16* __restrict__ Qn,
                                                   float* __restrict__ rowsum,
                                                   float* __restrict__ pickv) {
    const int bx   = blockIdx.x;
    const int ib   = bx >> 4;
    const int jq   = bx & 15;
    const int tid  = threadIdx.x;
    const int lane = tid & 63;
    const int w    = tid >> 6;
    const int l15  = lane & 15;
    const int lks  = lane >> 4;          // k-segment 0..3
    const int i0w  = ib * RPB + w * RPW;

    // A fragments: 64 rows x K=256 -> a[4][8] (128 regs).
    bf16x8 a[4][8];
    {
        const __hip_bfloat16* ab = En + (size_t)(i0w + l15) * DIM + lks * 8;
#pragma unroll
        for (int mi = 0; mi < 4; ++mi)
#pragma unroll
            for (int kk = 0; kk < 8; ++kk)
                a[mi][kk] = *reinterpret_cast<const bf16x8*>(ab + mi * 16 * DIM + kk * 32);
    }

    float racc[4][4];
#pragma unroll
    for (int mi = 0; mi < 4; ++mi)
#pragma unroll
        for (int r = 0; r < 4; ++r) racc[mi][r] = 0.0f;

    const int jq0 = jq * JSPAN;
    // Per-lane B base: within each 1KB chunk, lane reads bytes
    // [(lane&15)*64 + (lane>>4)*16, +16) - the 64 lanes tile the chunk.
    const char* qlane = (const char*)Qn + (size_t)jq0 * 512 + l15 * 64 + lks * 16;

    auto loadB = [&](bf16x8 (&b)[8], int p) {
        const char* gp = qlane + (size_t)p * GRP_BYTES;
#pragma unroll
        for (int kk = 0; kk < 8; ++kk)
            b[kk] = *reinterpret_cast<const bf16x8*>(gp + kk * 1024);
    };

    // MFMA group p (fragments already in registers) + exp2 epilogue.
    // C/D layout: col = lane&15, row = (lane>>4)*4 + r. acc = -log2e*s.
    auto step = [&](const bf16x8 (&b)[8], int p) {
        f32x4 acc[4];
#pragma unroll
        for (int mi = 0; mi < 4; ++mi) acc[mi] = f32x4{0.f, 0.f, 0.f, 0.f};

        __builtin_amdgcn_s_setprio(1);
#pragma unroll
        for (int kk = 0; kk < 8; ++kk)
#pragma unroll
            for (int mi = 0; mi < 4; ++mi)
                acc[mi] = __builtin_amdgcn_mfma_f32_16x16x32_bf16(
                    a[mi][kk], b[kk], acc[mi], 0, 0, 0);
        __builtin_amdgcn_s_setprio(0);

        const int grpbase = jq0 + p * 16;
        const bool spec = (grpbase <= i0w + RPW) && (grpbase + 16 > i0w);
        if (!spec) {
#pragma unroll
            for (int mi = 0; mi < 4; ++mi)
#pragma unroll
                for (int r = 0; r < 4; ++r)
                    racc[mi][r] += __builtin_amdgcn_exp2f(acc[mi][r]);
        } else {
            const int jg = grpbase + l15;
#pragma unroll
            for (int mi = 0; mi < 4; ++mi) {
                const int ig0 = i0w + mi * 16 + lks * 4;
#pragma unroll
                for (int r = 0; r < 4; ++r) {
                    const float e  = __builtin_amdgcn_exp2f(acc[mi][r]);
                    const int   ig = ig0 + r;
                    racc[mi][r] += (jg == ig) ? 0.0f : e;
                    const int pc = (ig == NROWS - 1) ? (NROWS - 2) : (ig + 1);
                    if (jg == pc) pickv[ig] = acc[mi][r] * NEG_LN2;  // recover s
                }
            }
        }
    };

    // Depth-2 register pipeline. Steady state: 16 loads outstanding after
    // issue; vmcnt(8) retires the older group, leaves the newer in flight.
    bf16x8 bA[8], bB[8];
    loadB(bA, 0);
    loadB(bB, 1);

    for (int pp = 0; pp < NGRP; pp += 2) {
        if (pp == NGRP - 2) asm volatile("s_waitcnt vmcnt(8)" ::: "memory");
        else                asm volatile("s_waitcnt vmcnt(8)" ::: "memory");
        step(bA, pp);                       // consume group pp
        if (pp + 2 < NGRP) loadB(bA, pp + 2);

        if (pp + 2 < NGRP) asm volatile("s_waitcnt vmcnt(8)" ::: "memory");
        else               asm volatile("s_waitcnt vmcnt(0)" ::: "memory");
        step(bB, pp + 1);                   // consume group pp+1
        if (pp + 3 < NGRP) loadB(bB, pp + 3);
    }

    // Reduce row partials across the 16 col-lanes, one atomicAdd per row.
#pragma unroll
    for (int mi = 0; mi < 4; ++mi)
#pragma unroll
        for (int r = 0; r < 4; ++r) {
            float v = racc[mi][r];
            v += __shfl_xor(v, 1, 64);
            v += __shfl_xor(v, 2, 64);
            v += __shfl_xor(v, 4, 64);
            v += __shfl_xor(v, 8, 64);
            if (l15 == 0) atomicAdd(&rowsum[i0w + mi * 16 + lks * 4 + r], v);
        }
}

// ---- Kernel 3: final reduce, 16 blocks, one atomicAdd each (out pre-zeroed) ----
__global__ __launch_bounds__(256) void k_finalize(const float* __restrict__ rowsum,
                                                  const float* __restrict__ pickv,
                                                  float* __restrict__ out) {
    __shared__ float red[4];
    const int base = blockIdx.x * 512;
    float s = 0.0f;
#pragma unroll
    for (int it = 0; it < 2; ++it) {
        const int i = base + it * 256 + threadIdx.x;
        s += __logf(rowsum[i]) + pickv[i];
    }
#pragma unroll
    for (int m = 32; m >= 1; m >>= 1) s += __shfl_xor(s, m, 64);
    if ((threadIdx.x & 63) == 0) red[threadIdx.x >> 6] = s;
    __syncthreads();
    if (threadIdx.x == 0)
        atomicAdd(out, (red[0] + red[1] + red[2] + red[3]) * (1.0f / (float)NROWS));
}

extern "C" void kernel_launch(void* const* d_in, const int* in_sizes, int n_in,
                              void* d_out, int out_size, void* d_ws, size_t ws_size,
                              hipStream_t stream) {
    const float* emb = (const float*)d_in[0];
    const float* qry = (const float*)d_in[1];
    float* out = (float*)d_out;

    char* ws = (char*)d_ws;
    __hip_bfloat16* En = (__hip_bfloat16*)ws;                                  // 4 MB row-major
    __hip_bfloat16* Qn = (__hip_bfloat16*)(ws + (size_t)NROWS * DIM * 2);      // 4 MB K-major-grouped
    float* rowsum = (float*)(ws + (size_t)NROWS * DIM * 4);                    // 32 KB
    float* pickv  = rowsum + NROWS;                                            // 32 KB

    k_normalize_all<<<2 * NROWS / 4, 256, 0, stream>>>(emb, qry, En, Qn, rowsum, out);
    k_simlse<<<32 * NSPLIT, 256, 0, stream>>>(En, Qn, rowsum, pickv);
    k_finalize<<<16, 256, 0, stream>>>(rowsum, pickv, out);
}

// Round 15
// 50.968 us; speedup vs baseline: 1.3856x; 1.3856x over previous
//
#include <hip/hip_runtime.h>
#include <hip/hip_bf16.h>

#define NROWS 8192
#define DIM 256
#define NSPLIT 16
#define JSPAN (NROWS / NSPLIT)   /* 512 cols per block */
#define TILE_COLS 64
#define TILE_BYTES (TILE_COLS * 512)  /* 32 KB */
#define NT (JSPAN / TILE_COLS)   /* 8 tiles per block */
#define RPW 64                   /* rows per wave (A stationary) */
#define RPB 512                  /* rows per block (8 waves) */
#define GRP_BYTES 8192           /* 16 cols x 512 B, K-major-grouped */

typedef __bf16 bf16x8 __attribute__((ext_vector_type(8)));
typedef float f32x4 __attribute__((ext_vector_type(4)));

#define NEG_LOG2E -1.4426950408889634f
#define NEG_LN2   -0.6931471805599453f

// ---- Kernel 1: L2-normalize rows, fp32 -> bf16; zero accums ----
// En: row-major, scaled by -log2(e) (GEMM acc = -log2e*sim; exp(-sim)=exp2(acc)).
// Qn: K-MAJOR-GROUPED. Group g = cols [16g,16g+16); chunk kk (1 KB) = the 16
// cols' 64B K-slice kk, col-interleaved at 64B:
//   byte(col=16g+c, kbyte=kk*64+b) -> Qn + g*8192 + kk*1024 + c*64 + b.
__global__ __launch_bounds__(256) void k_normalize_all(const float* __restrict__ emb,
                                                       const float* __restrict__ qry,
                                                       __hip_bfloat16* __restrict__ En,
                                                       __hip_bfloat16* __restrict__ Qn,
                                                       float* __restrict__ rowsum,
                                                       float* __restrict__ out) {
    if (blockIdx.x < 8)
        reinterpret_cast<float4*>(rowsum)[blockIdx.x * 256 + threadIdx.x] =
            float4{0.f, 0.f, 0.f, 0.f};
    if (blockIdx.x == 8 && threadIdx.x == 0) out[0] = 0.f;

    const int gr   = blockIdx.x * 4 + (threadIdx.x >> 6);
    const int lane = threadIdx.x & 63;
    const bool isE = (gr < NROWS);
    const float* in = isE ? emb : qry;
    const int row   = isE ? gr : gr - NROWS;
    const float scale = isE ? NEG_LOG2E : 1.0f;

    const float4 v = reinterpret_cast<const float4*>(in + (size_t)row * DIM)[lane];
    float ss = v.x * v.x + v.y * v.y + v.z * v.z + v.w * v.w;
#pragma unroll
    for (int m = 32; m >= 1; m >>= 1) ss += __shfl_xor(ss, m, 64);
    const float inv = scale / fmaxf(sqrtf(ss), 1e-8f);
    __hip_bfloat16 o[4];
    o[0] = __float2bfloat16(v.x * inv);
    o[1] = __float2bfloat16(v.y * inv);
    o[2] = __float2bfloat16(v.z * inv);
    o[3] = __float2bfloat16(v.w * inv);
    const ushort4 o8 = *reinterpret_cast<const ushort4*>(o);

    if (isE) {
        reinterpret_cast<ushort4*>(En + (size_t)row * DIM)[lane] = o8;
    } else {
        const int g = row >> 4, c = row & 15;
        char* dst = (char*)Qn + (size_t)g * GRP_BYTES
                    + (size_t)(lane >> 3) * 1024 + c * 64 + (lane & 7) * 8;
        *reinterpret_cast<ushort4*>(dst) = o8;
    }
}

// ---- Kernel 2: fused sim-GEMM + row sum of exp(-s), BLOCK-SHARED staging ----
// 512 threads = 8 waves; each wave owns 64 stationary A-rows (a[4][8], 128
// VGPR); the 8 waves SHARE one 64-col B tile (32 KB) per step -> staged
// traffic drops 8x vs wave-private (r12 was staging-BW-bound at ~20 B/cy/CU).
// K-major-grouped Qn: DMA = contiguous 1KB identity copies (each wave stages
// its 4 chunks); ds_read = lane*16-tiled 1KB chunks, conflict-free, offsets
// immediate. Ring-2 LDS (64 KB), depth-1 prefetch: stage(t+1) issued at the
// top of step t, one vmcnt(0)+barrier at the end (issue-to-wait gap = a full
// ~4000-cy step >> L2 latency). 128 MFMA/wave/step.
__global__ __launch_bounds__(512, 2) void k_simlse(const __hip_bfloat16* __restrict__ En,
                                                   const __hip_bfloat16* __restrict__ Qn,
                                                   float* __restrict__ rowsum,
                                                   float* __restrict__ pickv) {
    __shared__ char lds[2][TILE_BYTES];   // 64 KB ring
    const int bx   = blockIdx.x;
    const int ib   = bx >> 4;
    const int jq   = bx & 15;
    const int tid  = threadIdx.x;
    const int lane = tid & 63;
    const int w    = tid >> 6;           // wave 0..7
    const int l15  = lane & 15;
    const int lks  = lane >> 4;          // k-segment 0..3
    const int i0w  = ib * RPB + w * RPW;

    // A fragments: 64 rows x K=256 -> a[4][8] (128 regs).
    bf16x8 a[4][8];
    {
        const __hip_bfloat16* ab = En + (size_t)(i0w + l15) * DIM + lks * 8;
#pragma unroll
        for (int mi = 0; mi < 4; ++mi)
#pragma unroll
            for (int kk = 0; kk < 8; ++kk)
                a[mi][kk] = *reinterpret_cast<const bf16x8*>(ab + mi * 16 * DIM + kk * 32);
    }

    float racc[4][4];
#pragma unroll
    for (int mi = 0; mi < 4; ++mi)
#pragma unroll
        for (int r = 0; r < 4; ++r) racc[mi][r] = 0.0f;

    const int jq0 = jq * JSPAN;
    // Tile t source: contiguous 32KB at qbase + t*TILE_BYTES. Wave w stages
    // chunks [4w, 4w+4) (1KB each, identity copy).
    const char* qtile = (const char*)Qn + (size_t)jq0 * 512 + (size_t)lane * 16
                        + (size_t)w * 4096;

    auto stage_tile = [&](const char* src, char* buf) {
#pragma unroll
        for (int i = 0; i < 4; ++i)
            __builtin_amdgcn_global_load_lds(
                (const __attribute__((address_space(1))) void*)(src + i * 1024),
                (__attribute__((address_space(3))) void*)(buf + w * 4096 + i * 1024),
                16, 0, 0);
    };

    // Prologue: stage tile 0, drain own 4 DMAs, barrier.
    stage_tile(qtile, lds[0]);
    asm volatile("s_waitcnt vmcnt(0)" ::: "memory");
    __builtin_amdgcn_s_barrier();

    for (int t = 0; t < NT; ++t) {
        const char* cur = lds[t & 1];
        char* nxt       = lds[(t + 1) & 1];
        if (t + 1 < NT) stage_tile(qtile + TILE_BYTES, nxt);
        qtile += TILE_BYTES;

        const char* rd = cur + l15 * 64 + lks * 16;   // conflict-free frag base
        const int tbase = jq0 + t * TILE_COLS;

#pragma unroll
        for (int g = 0; g < 4; ++g) {
            bf16x8 b[8];
#pragma unroll
            for (int kk = 0; kk < 8; ++kk)
                b[kk] = *reinterpret_cast<const bf16x8*>(rd + (g * 8 + kk) * 1024);

            f32x4 acc[4];
#pragma unroll
            for (int mi = 0; mi < 4; ++mi) acc[mi] = f32x4{0.f, 0.f, 0.f, 0.f};

            __builtin_amdgcn_s_setprio(1);
#pragma unroll
            for (int kk = 0; kk < 8; ++kk)
#pragma unroll
                for (int mi = 0; mi < 4; ++mi)
                    acc[mi] = __builtin_amdgcn_mfma_f32_16x16x32_bf16(
                        a[mi][kk], b[kk], acc[mi], 0, 0, 0);
            __builtin_amdgcn_s_setprio(0);

            // Epilogue. acc = -log2e*s; exp(-s) = exp2(acc).
            // C/D layout: col = lane&15, row = (lane>>4)*4 + r.
            const int grpbase = tbase + g * 16;
            const bool spec = (grpbase <= i0w + RPW) && (grpbase + 16 > i0w);
            if (!spec) {
#pragma unroll
                for (int mi = 0; mi < 4; ++mi)
#pragma unroll
                    for (int r = 0; r < 4; ++r)
                        racc[mi][r] += __builtin_amdgcn_exp2f(acc[mi][r]);
            } else {
                const int jg = grpbase + l15;
#pragma unroll
                for (int mi = 0; mi < 4; ++mi) {
                    const int ig0 = i0w + mi * 16 + lks * 4;
#pragma unroll
                    for (int r = 0; r < 4; ++r) {
                        const float e  = __builtin_amdgcn_exp2f(acc[mi][r]);
                        const int   ig = ig0 + r;
                        racc[mi][r] += (jg == ig) ? 0.0f : e;
                        const int pc = (ig == NROWS - 1) ? (NROWS - 2) : (ig + 1);
                        if (jg == pc) pickv[ig] = acc[mi][r] * NEG_LN2;  // recover s
                    }
                }
            }
        }

        if (t + 1 < NT) {
            // Own 4 DMAs for tile t+1 were issued a full step (~4000 cy) ago:
            // this drain is instant. Barrier => tile t+1 resident block-wide,
            // and everyone is done reading the buffer stage(t+2) overwrites.
            asm volatile("s_waitcnt vmcnt(0)" ::: "memory");
            __builtin_amdgcn_s_barrier();
        }
    }

    // Reduce row partials across the 16 col-lanes, one atomicAdd per row.
#pragma unroll
    for (int mi = 0; mi < 4; ++mi)
#pragma unroll
        for (int r = 0; r < 4; ++r) {
            float v = racc[mi][r];
            v += __shfl_xor(v, 1, 64);
            v += __shfl_xor(v, 2, 64);
            v += __shfl_xor(v, 4, 64);
            v += __shfl_xor(v, 8, 64);
            if (l15 == 0) atomicAdd(&rowsum[i0w + mi * 16 + lks * 4 + r], v);
        }
}

// ---- Kernel 3: final reduce, 16 blocks, one atomicAdd each (out pre-zeroed) ----
__global__ __launch_bounds__(256) void k_finalize(const float* __restrict__ rowsum,
                                                  const float* __restrict__ pickv,
                                                  float* __restrict__ out) {
    __shared__ float red[4];
    const int base = blockIdx.x * 512;
    float s = 0.0f;
#pragma unroll
    for (int it = 0; it < 2; ++it) {
        const int i = base + it * 256 + threadIdx.x;
        s += __logf(rowsum[i]) + pickv[i];
    }
#pragma unroll
    for (int m = 32; m >= 1; m >>= 1) s += __shfl_xor(s, m, 64);
    if ((threadIdx.x & 63) == 0) red[threadIdx.x >> 6] = s;
    __syncthreads();
    if (threadIdx.x == 0)
        atomicAdd(out, (red[0] + red[1] + red[2] + red[3]) * (1.0f / (float)NROWS));
}

extern "C" void kernel_launch(void* const* d_in, const int* in_sizes, int n_in,
                              void* d_out, int out_size, void* d_ws, size_t ws_size,
                              hipStream_t stream) {
    const float* emb = (const float*)d_in[0];
    const float* qry = (const float*)d_in[1];
    float* out = (float*)d_out;

    char* ws = (char*)d_ws;
    __hip_bfloat16* En = (__hip_bfloat16*)ws;                                  // 4 MB row-major
    __hip_bfloat16* Qn = (__hip_bfloat16*)(ws + (size_t)NROWS * DIM * 2);      // 4 MB K-major-grouped
    float* rowsum = (float*)(ws + (size_t)NROWS * DIM * 4);                    // 32 KB
    float* pickv  = rowsum + NROWS;                                            // 32 KB

    k_normalize_all<<<2 * NROWS / 4, 256, 0, stream>>>(emb, qry, En, Qn, rowsum, out);
    k_simlse<<<16 * NSPLIT, 512, 0, stream>>>(En, Qn, rowsum, pickv);
    k_finalize<<<16, 256, 0, stream>>>(rowsum, pickv, out);
}

// Round 16
// 49.569 us; speedup vs baseline: 1.4247x; 1.0282x over previous
//
#include <hip/hip_runtime.h>
#include <hip/hip_bf16.h>

#define NROWS 8192
#define DIM 256
#define NSPLIT 16
#define JSPAN (NROWS / NSPLIT)   /* 512 cols per block */
#define TILE_COLS 64
#define TILE_BYTES (TILE_COLS * 512)  /* 32 KB */
#define NT (JSPAN / TILE_COLS)   /* 8 tiles per block */
#define RPW 32                   /* rows per wave (A stationary, halved for occupancy) */
#define RPB 256                  /* rows per block (8 waves x 32) */
#define GRP_BYTES 8192           /* 16 cols x 512 B, K-major-grouped */

typedef __bf16 bf16x8 __attribute__((ext_vector_type(8)));
typedef float f32x4 __attribute__((ext_vector_type(4)));

#define NEG_LOG2E -1.4426950408889634f
#define NEG_LN2   -0.6931471805599453f

// ---- Kernel 1: L2-normalize rows, fp32 -> bf16; zero accums ----
// En: row-major, scaled by -log2(e) (GEMM acc = -log2e*sim; exp(-sim)=exp2(acc)).
// Qn: K-MAJOR-GROUPED. Group g = cols [16g,16g+16); chunk kk (1 KB) = the 16
// cols' 64B K-slice kk, col-interleaved at 64B:
//   byte(col=16g+c, kbyte=kk*64+b) -> Qn + g*8192 + kk*1024 + c*64 + b.
__global__ __launch_bounds__(256) void k_normalize_all(const float* __restrict__ emb,
                                                       const float* __restrict__ qry,
                                                       __hip_bfloat16* __restrict__ En,
                                                       __hip_bfloat16* __restrict__ Qn,
                                                       float* __restrict__ rowsum,
                                                       float* __restrict__ out) {
    if (blockIdx.x < 8)
        reinterpret_cast<float4*>(rowsum)[blockIdx.x * 256 + threadIdx.x] =
            float4{0.f, 0.f, 0.f, 0.f};
    if (blockIdx.x == 8 && threadIdx.x == 0) out[0] = 0.f;

    const int gr   = blockIdx.x * 4 + (threadIdx.x >> 6);
    const int lane = threadIdx.x & 63;
    const bool isE = (gr < NROWS);
    const float* in = isE ? emb : qry;
    const int row   = isE ? gr : gr - NROWS;
    const float scale = isE ? NEG_LOG2E : 1.0f;

    const float4 v = reinterpret_cast<const float4*>(in + (size_t)row * DIM)[lane];
    float ss = v.x * v.x + v.y * v.y + v.z * v.z + v.w * v.w;
#pragma unroll
    for (int m = 32; m >= 1; m >>= 1) ss += __shfl_xor(ss, m, 64);
    const float inv = scale / fmaxf(sqrtf(ss), 1e-8f);
    __hip_bfloat16 o[4];
    o[0] = __float2bfloat16(v.x * inv);
    o[1] = __float2bfloat16(v.y * inv);
    o[2] = __float2bfloat16(v.z * inv);
    o[3] = __float2bfloat16(v.w * inv);
    const ushort4 o8 = *reinterpret_cast<const ushort4*>(o);

    if (isE) {
        reinterpret_cast<ushort4*>(En + (size_t)row * DIM)[lane] = o8;
    } else {
        const int g = row >> 4, c = row & 15;
        char* dst = (char*)Qn + (size_t)g * GRP_BYTES
                    + (size_t)(lane >> 3) * 1024 + c * 64 + (lane & 7) * 8;
        *reinterpret_cast<ushort4*>(dst) = o8;
    }
}

// ---- Kernel 2: fused sim-GEMM + row sum of exp(-s), occupancy-first ----
// 8 waves/block, 32 rows/wave (a[2][8] = 64 VGPR) -> total VGPR <= 128 under
// __launch_bounds__(512,4): 4 waves/SIMD, 2 INDEPENDENT blocks/CU. This is
// the round's single change vs r15 (which was VGPR~200 -> 2 waves/SIMD,
// 1 block/CU, nothing to hide barrier bubbles with).
// Staging unchanged: 8 waves share one 64-col K-major-grouped tile; DMA =
// contiguous 1KB identity copies; ds_read = lane*16-tiled chunks (conflict-
// free, immediate offsets); ring-2 LDS, depth-1 prefetch, one vmcnt+barrier
// per step issued a full ~5000-cy step ahead.
__global__ __launch_bounds__(512, 4) void k_simlse(const __hip_bfloat16* __restrict__ En,
                                                   const __hip_bfloat16* __restrict__ Qn,
                                                   float* __restrict__ rowsum,
                                                   float* __restrict__ pickv) {
    __shared__ char lds[2][TILE_BYTES];   // 64 KB ring
    const int bx   = blockIdx.x;
    const int ib   = bx >> 4;            // 0..31
    const int jq   = bx & 15;
    const int tid  = threadIdx.x;
    const int lane = tid & 63;
    const int w    = tid >> 6;           // wave 0..7
    const int l15  = lane & 15;
    const int lks  = lane >> 4;          // k-segment 0..3
    const int i0w  = ib * RPB + w * RPW;

    // A fragments: 32 rows x K=256 -> a[2][8] (64 regs).
    bf16x8 a[2][8];
    {
        const __hip_bfloat16* ab = En + (size_t)(i0w + l15) * DIM + lks * 8;
#pragma unroll
        for (int mi = 0; mi < 2; ++mi)
#pragma unroll
            for (int kk = 0; kk < 8; ++kk)
                a[mi][kk] = *reinterpret_cast<const bf16x8*>(ab + mi * 16 * DIM + kk * 32);
    }

    float racc[2][4];
#pragma unroll
    for (int mi = 0; mi < 2; ++mi)
#pragma unroll
        for (int r = 0; r < 4; ++r) racc[mi][r] = 0.0f;

    const int jq0 = jq * JSPAN;
    // Tile t source: contiguous 32KB. Wave w stages chunks [4w, 4w+4).
    const char* qtile = (const char*)Qn + (size_t)jq0 * 512 + (size_t)lane * 16
                        + (size_t)w * 4096;

    auto stage_tile = [&](const char* src, char* buf) {
#pragma unroll
        for (int i = 0; i < 4; ++i)
            __builtin_amdgcn_global_load_lds(
                (const __attribute__((address_space(1))) void*)(src + i * 1024),
                (__attribute__((address_space(3))) void*)(buf + w * 4096 + i * 1024),
                16, 0, 0);
    };

    // Prologue: stage tile 0, drain own 4 DMAs, barrier.
    stage_tile(qtile, lds[0]);
    asm volatile("s_waitcnt vmcnt(0)" ::: "memory");
    __builtin_amdgcn_s_barrier();

    for (int t = 0; t < NT; ++t) {
        const char* cur = lds[t & 1];
        char* nxt       = lds[(t + 1) & 1];
        if (t + 1 < NT) stage_tile(qtile + TILE_BYTES, nxt);
        qtile += TILE_BYTES;

        const char* rd = cur + l15 * 64 + lks * 16;   // conflict-free frag base
        const int tbase = jq0 + t * TILE_COLS;

#pragma unroll
        for (int g = 0; g < 4; ++g) {
            f32x4 acc[2];
            acc[0] = f32x4{0.f, 0.f, 0.f, 0.f};
            acc[1] = f32x4{0.f, 0.f, 0.f, 0.f};

            // Interleaved b-load + MFMA: live b = 1 fragment (4 VGPR), keeps
            // total register pressure under the 128 cap (no spill).
            __builtin_amdgcn_s_setprio(1);
#pragma unroll
            for (int kk = 0; kk < 8; ++kk) {
                const bf16x8 b = *reinterpret_cast<const bf16x8*>(rd + (g * 8 + kk) * 1024);
                acc[0] = __builtin_amdgcn_mfma_f32_16x16x32_bf16(a[0][kk], b, acc[0], 0, 0, 0);
                acc[1] = __builtin_amdgcn_mfma_f32_16x16x32_bf16(a[1][kk], b, acc[1], 0, 0, 0);
            }
            __builtin_amdgcn_s_setprio(0);

            // Epilogue. acc = -log2e*s; exp(-s) = exp2(acc).
            // C/D layout: col = lane&15, row = (lane>>4)*4 + r.
            const int grpbase = tbase + g * 16;
            const bool spec = (grpbase <= i0w + RPW) && (grpbase + 16 > i0w);
            if (!spec) {
#pragma unroll
                for (int mi = 0; mi < 2; ++mi)
#pragma unroll
                    for (int r = 0; r < 4; ++r)
                        racc[mi][r] += __builtin_amdgcn_exp2f(acc[mi][r]);
            } else {
                const int jg = grpbase + l15;
#pragma unroll
                for (int mi = 0; mi < 2; ++mi) {
                    const int ig0 = i0w + mi * 16 + lks * 4;
#pragma unroll
                    for (int r = 0; r < 4; ++r) {
                        const float e  = __builtin_amdgcn_exp2f(acc[mi][r]);
                        const int   ig = ig0 + r;
                        racc[mi][r] += (jg == ig) ? 0.0f : e;
                        const int pc = (ig == NROWS - 1) ? (NROWS - 2) : (ig + 1);
                        if (jg == pc) pickv[ig] = acc[mi][r] * NEG_LN2;  // recover s
                    }
                }
            }
        }

        if (t + 1 < NT) {
            // Own DMAs for tile t+1 were issued a full step ago: near-instant.
            asm volatile("s_waitcnt vmcnt(0)" ::: "memory");
            __builtin_amdgcn_s_barrier();
        }
    }

    // Reduce row partials across the 16 col-lanes, one atomicAdd per row.
#pragma unroll
    for (int mi = 0; mi < 2; ++mi)
#pragma unroll
        for (int r = 0; r < 4; ++r) {
            float v = racc[mi][r];
            v += __shfl_xor(v, 1, 64);
            v += __shfl_xor(v, 2, 64);
            v += __shfl_xor(v, 4, 64);
            v += __shfl_xor(v, 8, 64);
            if (l15 == 0) atomicAdd(&rowsum[i0w + mi * 16 + lks * 4 + r], v);
        }
}

// ---- Kernel 3: final reduce, 16 blocks, one atomicAdd each (out pre-zeroed) ----
__global__ __launch_bounds__(256) void k_finalize(const float* __restrict__ rowsum,
                                                  const float* __restrict__ pickv,
                                                  float* __restrict__ out) {
    __shared__ float red[4];
    const int base = blockIdx.x * 512;
    float s = 0.0f;
#pragma unroll
    for (int it = 0; it < 2; ++it) {
        const int i = base + it * 256 + threadIdx.x;
        s += __logf(rowsum[i]) + pickv[i];
    }
#pragma unroll
    for (int m = 32; m >= 1; m >>= 1) s += __shfl_xor(s, m, 64);
    if ((threadIdx.x & 63) == 0) red[threadIdx.x >> 6] = s;
    __syncthreads();
    if (threadIdx.x == 0)
        atomicAdd(out, (red[0] + red[1] + red[2] + red[3]) * (1.0f / (float)NROWS));
}

extern "C" void kernel_launch(void* const* d_in, const int* in_sizes, int n_in,
                              void* d_out, int out_size, void* d_ws, size_t ws_size,
                              hipStream_t stream) {
    const float* emb = (const float*)d_in[0];
    const float* qry = (const float*)d_in[1];
    float* out = (float*)d_out;

    char* ws = (char*)d_ws;
    __hip_bfloat16* En = (__hip_bfloat16*)ws;                                  // 4 MB row-major
    __hip_bfloat16* Qn = (__hip_bfloat16*)(ws + (size_t)NROWS * DIM * 2);      // 4 MB K-major-grouped
    float* rowsum = (float*)(ws + (size_t)NROWS * DIM * 4);                    // 32 KB
    float* pickv  = rowsum + NROWS;                                            // 32 KB

    k_normalize_all<<<2 * NROWS / 4, 256, 0, stream>>>(emb, qry, En, Qn, rowsum, out);
    k_simlse<<<32 * NSPLIT, 512, 0, stream>>>(En, Qn, rowsum, pickv);
    k_finalize<<<16, 256, 0, stream>>>(rowsum, pickv, out);
}